// Round 9
// baseline (563.362 us; speedup 1.0000x reference)
//
#include <hip/hip_runtime.h>
#include <hip/hip_bf16.h>

#define NN 512
#define DEG 8
#define FD 128
#define HD 256
#define MD 256
#define OD 64
#define PD 2
#define HIST 10
#define TOTAL (10 * NN)       /* 5120 queue entries processed */
#define NPAR 648              /* entries with children: i < (TOTAL-S)/8 <= 632 */
#define INV_SQRT_H 0.0625f

typedef __hip_bfloat16 bf16;

// bit-level finite guard (fast-math-proof)
__device__ __forceinline__ float finz(float x) {
  unsigned u = __float_as_uint(x);
  return (((u >> 23) & 0xFFu) == 0xFFu) ? 0.f : x;
}

// runtime-dtype load: bf=1 -> bf16 array, bf=0 -> float array
__device__ __forceinline__ float ldin(const void* p, int idx, int bf) {
  if (bf) return __bfloat162float(((const bf16*)p)[idx]);
  return ((const float*)p)[idx];
}

// device-coherent dword load/store (relaxed agent atomics -> flagged global op,
// bypasses non-coherent L2 for THIS access only; no cache-wide fences anywhere)
__device__ __forceinline__ float scload(const float* p) {
  return __uint_as_float(__hip_atomic_load((const unsigned*)p, __ATOMIC_RELAXED,
                                           __HIP_MEMORY_SCOPE_AGENT));
}
__device__ __forceinline__ void scstore(float* p, float v) {
  __hip_atomic_store((unsigned*)p, __float_as_uint(v), __ATOMIC_RELAXED,
                     __HIP_MEMORY_SCOPE_AGENT);
}

// ---- static device scratch ----
__device__ float g_hist[NN * HIST * HD];    // slot-0 encoded states (k_prep -> k_flow)
__device__ float g_msgb[NPAR * MD];         // messages of entries with children
__device__ float g_WQK[HD * HD];            // Wq@Wk^T, PAIR-INTERLEAVED: [(p*HD+t)*2+e]
__device__ float g_WrS[HD * HD];            // sum of 4 Wr row-blocks, same layout
__device__ float g_vq[HD];                  // Wq @ bk
__device__ float g_ck[HD];                  // Wk @ bq
__device__ float g_bqk;                     // bq . bk
__device__ int   g_node[TOTAL];
__device__ int   g_done[TOTAL];             // message-ready flags (parents only)
__device__ int   g_dtype;                   // 1 = float tensors are bf16
__device__ int   g_i64;                     // 1 = neighbors int64

__device__ __forceinline__ int decode_S(const int* dS) {
  int r = dS[0];
  if (r >= 1 && r <= NN) return r;
  float f = __int_as_float(r);
  if (f >= 1.f && f <= (float)NN) return (int)f;
  unsigned u = ((unsigned)r & 0xFFFFu) << 16;
  float g = __uint_as_float(u);
  if (g >= 1.f && g <= (float)NN) return (int)g;
  return 64;
}

__device__ __forceinline__ int get_nbr(const int* nbrs, int i64, int n, int d) {
  int v = i64 ? nbrs[2 * (n * DEG + d)] : nbrs[n * DEG + d];
  return (v < 0) ? 0 : (v >= NN ? NN - 1 : v);
}

// wave-parallel dtype probe: same predicate as the validated serial version,
// one ballot over the first 64 words instead of 64 serial loads.
__device__ __forceinline__ int detect_bf(const unsigned* xa_w) {
  const int lane = threadIdx.x & 63;
  unsigned lo = xa_w[lane] & 0xFFFFu;
  float av = fabsf(__uint_as_float(lo << 16));
  unsigned long long m = __ballot(av > 0.000244140625f && av < 64.f);
  return ((int)__popcll(m) >= 32) ? 1 : 0;
}

// ---------------- k_prep: weights fold + encode + BFS, ONE dispatch -----------------
// blocks 0..HD-1: WQK/WrS/vq rows; HD: ck/bqk; HD+1..HD+NN: encode; HD+NN+1: BFS.
// WQK/WrS written PAIR-INTERLEAVED: row b lands at [(b>>1)*HD + col]*2 + (b&1),
// so k_flow can read two K-rows per 8-byte load (blocks b, b^1 write disjoint floats
// of the same float2).
__global__ void __launch_bounds__(1024)
k_prep(const void* __restrict__ xa, const unsigned* __restrict__ xa_w,
       const int* __restrict__ nbrs, const int* __restrict__ dS,
       const void* __restrict__ We, const void* __restrict__ be,
       const void* __restrict__ Wq, const void* __restrict__ Wk,
       const void* __restrict__ Wr, const void* __restrict__ bq,
       const void* __restrict__ bk) {
  const int b = blockIdx.x, t = threadIdx.x;
  const int col = t & 255, grp = t >> 8;
  const int wave = t >> 6, lane = t & 63;
  const int bf = detect_bf(xa_w);
  if (t < 8) { int fi = 8 * b + t; if (fi < TOTAL) g_done[fi] = 0; }
  __shared__ float sw[HD];
  __shared__ float sp[4][HD];
  __shared__ float sr[16];
  __shared__ int s_node[TOTAL];              // BFS block only (20 KB)
  if (b < HD) {
    if (grp == 0) sw[col] = ldin(Wq, b * HD + col, bf);
    __syncthreads();
    {                                            // WQK[b][col], K split 4
      const int h0 = grp * 64;
      float a0 = 0.f, a1 = 0.f, a2 = 0.f, a3 = 0.f;
      for (int h = 0; h < 64; h += 4) {
        a0 += sw[h0 + h]     * ldin(Wk, col * HD + h0 + h,     bf);
        a1 += sw[h0 + h + 1] * ldin(Wk, col * HD + h0 + h + 1, bf);
        a2 += sw[h0 + h + 2] * ldin(Wk, col * HD + h0 + h + 2, bf);
        a3 += sw[h0 + h + 3] * ldin(Wk, col * HD + h0 + h + 3, bf);
      }
      sp[grp][col] = (a0 + a1) + (a2 + a3);
    }
    if (grp == 1) {                              // vq[b] partial (overlapped)
      float pv = sw[col] * ldin(bk, col, bf);
#pragma unroll
      for (int off = 32; off > 0; off >>= 1) pv += __shfl_down(pv, off, 64);
      if (lane == 0) sr[wave] = pv;              // waves 4..7
    }
    if (grp == 2) {                              // WrS row b (overlapped), interleaved
      float s = 0.f;
#pragma unroll
      for (int q = 0; q < 4; ++q) s += ldin(Wr, (size_t)(q * HD + b) * HD + col, bf);
      g_WrS[(((b >> 1) * HD) + col) * 2 + (b & 1)] = s;
    }
    __syncthreads();
    if (grp == 0)
      g_WQK[(((b >> 1) * HD) + col) * 2 + (b & 1)] =
          (sp[0][col] + sp[1][col]) + (sp[2][col] + sp[3][col]);
    if (t == 0) g_vq[b] = (sr[4] + sr[5]) + (sr[6] + sr[7]);
  } else if (b == HD) {
    {                                            // ck[col] = Wk row col . bq, split 4
      const int h0 = grp * 64;
      float a0 = 0.f, a1 = 0.f, a2 = 0.f, a3 = 0.f;
      for (int h = 0; h < 64; h += 4) {
        a0 += ldin(Wk, col * HD + h0 + h,     bf) * ldin(bq, h0 + h,     bf);
        a1 += ldin(Wk, col * HD + h0 + h + 1, bf) * ldin(bq, h0 + h + 1, bf);
        a2 += ldin(Wk, col * HD + h0 + h + 2, bf) * ldin(bq, h0 + h + 2, bf);
        a3 += ldin(Wk, col * HD + h0 + h + 3, bf) * ldin(bq, h0 + h + 3, bf);
      }
      sp[grp][col] = (a0 + a1) + (a2 + a3);
    }
    if (grp == 1) {
      float pb = ldin(bq, col, bf) * ldin(bk, col, bf);
#pragma unroll
      for (int off = 32; off > 0; off >>= 1) pb += __shfl_down(pb, off, 64);
      if (lane == 0) sr[wave] = pb;              // waves 4..7
    }
    __syncthreads();
    if (grp == 0)
      g_ck[col] = (sp[0][col] + sp[1][col]) + (sp[2][col] + sp[3][col]);
    if (t == 0) g_bqk = (sr[4] + sr[5]) + (sr[6] + sr[7]);
  } else if (b <= HD + NN) {                     // encode node n, K=FD split 4
    const int n = b - HD - 1;
    if (t < FD) sw[t] = ldin(xa, n * FD + t, bf);
    __syncthreads();
    const int f0 = grp * 32;
    float a0 = 0.f, a1 = 0.f, a2 = 0.f, a3 = 0.f;
    for (int f = 0; f < 32; f += 4) {
      a0 += sw[f0 + f]     * ldin(We, (f0 + f)     * HD + col, bf);
      a1 += sw[f0 + f + 1] * ldin(We, (f0 + f + 1) * HD + col, bf);
      a2 += sw[f0 + f + 2] * ldin(We, (f0 + f + 2) * HD + col, bf);
      a3 += sw[f0 + f + 3] * ldin(We, (f0 + f + 3) * HD + col, bf);
    }
    sp[grp][col] = (a0 + a1) + (a2 + a3);
    __syncthreads();
    if (grp == 0)
      g_hist[(size_t)(n * HIST) * HD + col] =
          ldin(be, col, bf) + (sp[0][col] + sp[1][col]) + (sp[2][col] + sp[3][col]);
  } else {                                       // BFS queue expansion
    if (t == 0) g_dtype = bf;
    bool c8 = (lane < 8) ? (nbrs[2 * lane + 1] == 0) : true;
    unsigned long long im = __ballot(c8);
    const int i64 = ((im & 0xFFull) == 0xFFull) ? 1 : 0;
    if (t == 0) g_i64 = i64;
    const int S = decode_S(dS);
    for (int i = t; i < S; i += 1024) s_node[i] = i;
    __syncthreads();
    int done = S;
    while (done < TOTAL) {                       // message tree, depth ~4
      long long nd = (long long)S + 8LL * (long long)done;
      int new_done = nd > (long long)TOTAL ? TOTAL : (int)nd;
      for (int i = done + t; i < new_done; i += 1024)
        s_node[i] = get_nbr(nbrs, i64, s_node[(i - S) >> 3], (i - S) & 7);
      __syncthreads();
      done = new_done;
    }
    for (int i = t; i < TOTAL; i += 1024) g_node[i] = s_node[i];
  }
}

// ---------------- dataflow executor: ONE BLOCK PER NODE + fused output --------------
// Round-8 structure (proven: 52 VGPR, clean traffic) with ONE change: the two hot
// matvecs read the PAIR-INTERLEAVED tables via float2 -> 128-iteration serial chain
// instead of 256 (two K-rows per 8-byte load, same coalescing, same total bytes).
// Residency: 512 blocks, launch_bounds(256,2), ~35 KB LDS -> 2 blocks/CU = all 512
// resident. Deps of entry e have smaller queue index -> progress by induction.
__global__ void __launch_bounds__(256, 2)
k_flow(const void* __restrict__ fmsg, const void* __restrict__ br_,
       const void* __restrict__ Wm, const void* __restrict__ bm,
       const void* __restrict__ Wd, const void* __restrict__ bd,
       void* __restrict__ out, const int* __restrict__ dS) {
  const int n = blockIdx.x;
  const int t = threadIdx.x;
  const int wave = t >> 6, lane = t & 63;
  const int S = decode_S(dS);
  const int bf = g_dtype;
  __shared__ float s_hist[HIST][HD];         // node-n ring buffer, column t private
  __shared__ float s_msgb2[2][MD];           // double-buffered message
  __shared__ float s_vals[HD];
  __shared__ float s_ns[HD];
  __shared__ float s_red[4][HIST + 1];
  __shared__ int   s_list[TOTAL];            // safe upper bound (20 KB)
  __shared__ int   s_cnt;
  __shared__ int   s_pf[2];                  // prefetch-done flag per buffer parity

  // loop invariants in registers
  const float rck = g_ck[t];
  const float rvq = g_vq[t];
  const float rbqk = g_bqk;
  const float rbr = ldin(br_, t, bf);
  const float rbm = ldin(bm, t, bf);
  const float2* wq2 = (const float2*)g_WQK + t;  // pair p at wq2[p*HD]
  const float2* wr2 = (const float2*)g_WrS + t;

#pragma unroll
  for (int j = 1; j < HIST; ++j) s_hist[j][t] = 0.f;   // invalid slots read as 0
  s_hist[0][t] = finz(g_hist[(size_t)n * HIST * HD + t]);  // encoded state

  if (wave == 0) {                           // build node-n entry list (queue order)
    int k = 0;
    for (int base = 0; base < TOTAL; base += 64) {
      int nd = g_node[base + lane];
      unsigned long long m = __ballot(nd == n);
      if (nd == n) {
        unsigned long long below = m & ((1ull << lane) - 1ull);
        s_list[k + (int)__popcll(below)] = base + lane;
      }
      k += (int)__popcll(m);
    }
    if (lane == 0) { s_cnt = k; s_pf[0] = 0; s_pf[1] = 0; }
  }
  __syncthreads();
  const int cnt = s_cnt;

  for (int k = 0; k < cnt; ++k) {
    const int e = s_list[k];
    const int c = k + 1;
    const int v = (c < HIST) ? c : HIST;
    const int slot = c % HIST;
    const bool hc = (S + 8 * e) < TOTAL;
    float* s_msg = s_msgb2[k & 1];
    const int havepf = s_pf[k & 1];          // written by t0 last step; end barrier

    // t0: decide prefetch for k+1 (flag may flip later -> blocking path catches it)
    if (t == 0) {
      int pf = 0;
      if (k + 1 < cnt) {
        const int e2 = s_list[k + 1];
        if (e2 < S) pf = 1;
        else pf = (__hip_atomic_load(&g_done[(e2 - S) >> 3], __ATOMIC_RELAXED,
                                     __HIP_MEMORY_SCOPE_AGENT) != 0);
      }
      s_pf[(k + 1) & 1] = pf;
    }

    // ---- acquire message (skipped when prefetched last step) ----
    if (!havepf) {
      if (e < S) {
        s_msg[t] = finz(ldin(fmsg, e * MD + t, bf));
      } else {
        const int p = (e - S) >> 3;
        if (t == 0)
          while (__hip_atomic_load(&g_done[p], __ATOMIC_RELAXED,
                                   __HIP_MEMORY_SCOPE_AGENT) == 0)
            __builtin_amdgcn_s_sleep(4);
        __syncthreads();                     // flag seen by whole block
        s_msg[t] = finz(scload(g_msgb + (size_t)p * MD + t));
      }
      __syncthreads();
    }

    // ---- kq[t] = msg . WQK[:,t] + ck[t] (pair-interleaved float2, 128 chain) ----
    float a0 = 0.f, a1 = 0.f, a2 = 0.f, a3 = 0.f;
#pragma unroll 2
    for (int p = 0; p < 128; p += 4) {
      const float2 w0 = wq2[(size_t)(p)     * HD];
      const float2 w1 = wq2[(size_t)(p + 1) * HD];
      const float2 w2 = wq2[(size_t)(p + 2) * HD];
      const float2 w3 = wq2[(size_t)(p + 3) * HD];
      a0 += s_msg[2 * p]     * w0.x + s_msg[2 * p + 1] * w0.y;
      a1 += s_msg[2 * p + 2] * w1.x + s_msg[2 * p + 3] * w1.y;
      a2 += s_msg[2 * p + 4] * w2.x + s_msg[2 * p + 5] * w2.y;
      a3 += s_msg[2 * p + 6] * w3.x + s_msg[2 * p + 7] * w3.y;
    }
    const float kq = rck + ((a0 + a1) + (a2 + a3));

    // ---- 11 dot-products via wave shuffle + LDS fold ----
    float part[HIST + 1];
#pragma unroll
    for (int j = 0; j < HIST; ++j) part[j] = s_hist[j][t] * kq;
    part[HIST] = s_msg[t] * rvq;
#pragma unroll
    for (int o = 32; o > 0; o >>= 1) {
#pragma unroll
      for (int j = 0; j <= HIST; ++j) part[j] += __shfl_down(part[j], o, 64);
    }
    if (lane == 0) {
#pragma unroll
      for (int j = 0; j <= HIST; ++j) s_red[wave][j] = part[j];
    }
    __syncthreads();                         // scores-fold barrier (s_pf visible too)

    // ---- issue next-message prefetch into a register (write to LDS deferred) ----
    const int dopf = s_pf[(k + 1) & 1];
    float pm = 0.f;
    if (dopf) {
      const int e2 = s_list[k + 1];
      pm = (e2 < S) ? ldin(fmsg, e2 * MD + t, bf)
                    : scload(g_msgb + (size_t)((e2 - S) >> 3) * MD + t);
    }

    float sc[HIST + 1];
#pragma unroll
    for (int j = 0; j <= HIST; ++j)
      sc[j] = (s_red[0][j] + s_red[1][j]) + (s_red[2][j] + s_red[3][j]);
    const float bkq = sc[HIST] + rbqk;
    float lg[HIST];
#pragma unroll
    for (int j = 0; j < HIST; ++j)
      lg[j] = (j < v) ? ((sc[j] + bkq) * INV_SQRT_H) : -1e30f;
    float mx = lg[0];
#pragma unroll
    for (int j = 1; j < HIST; ++j) mx = fmaxf(mx, lg[j]);
    float e_[HIST], den = 0.f;
#pragma unroll
    for (int j = 0; j < HIST; ++j) { e_[j] = __expf(lg[j] - mx); den += e_[j]; }
    const float iden = 1.0f / den;
    float val = 0.f;
#pragma unroll
    for (int j = 0; j < HIST; ++j) val += e_[j] * s_hist[j][t];
    s_vals[t] = val * iden;
    __syncthreads();

    // ---- ns = vals @ WrS + br (pair-interleaved float2, 128 chain) ----
    float b0 = 0.f, b1 = 0.f, b2 = 0.f, b3 = 0.f;
#pragma unroll 2
    for (int p = 0; p < 128; p += 4) {
      const float2 w0 = wr2[(size_t)(p)     * HD];
      const float2 w1 = wr2[(size_t)(p + 1) * HD];
      const float2 w2 = wr2[(size_t)(p + 2) * HD];
      const float2 w3 = wr2[(size_t)(p + 3) * HD];
      b0 += s_vals[2 * p]     * w0.x + s_vals[2 * p + 1] * w0.y;
      b1 += s_vals[2 * p + 2] * w1.x + s_vals[2 * p + 3] * w1.y;
      b2 += s_vals[2 * p + 4] * w2.x + s_vals[2 * p + 5] * w2.y;
      b3 += s_vals[2 * p + 6] * w3.x + s_vals[2 * p + 7] * w3.y;
    }
    const float ns = rbr + ((b0 + b1) + (b2 + b3));
    s_hist[slot][t] = ns;                    // column-private
    if (hc) s_ns[t] = ns;
    if (dopf) s_msgb2[(k + 1) & 1][t] = finz(pm);  // deferred prefetch commit
    __syncthreads();                         // s_ns + prefetched msg visible

    // ---- newmessage = [ns; msg] @ Wm + bm (parents only) ----
    if (hc) {
      float c0 = 0.f, c1 = 0.f, c2 = 0.f, c3 = 0.f;
      if (bf) {
        const bf16* w = (const bf16*)Wm;
        for (int h = 0; h < HD; h += 4) {
          c0 += s_ns[h]     * __bfloat162float(w[(h)     * MD + t]);
          c1 += s_ns[h + 1] * __bfloat162float(w[(h + 1) * MD + t]);
          c2 += s_ns[h + 2] * __bfloat162float(w[(h + 2) * MD + t]);
          c3 += s_ns[h + 3] * __bfloat162float(w[(h + 3) * MD + t]);
        }
        for (int m = 0; m < MD; m += 4) {
          c0 += s_msg[m]     * __bfloat162float(w[(HD + m)     * MD + t]);
          c1 += s_msg[m + 1] * __bfloat162float(w[(HD + m + 1) * MD + t]);
          c2 += s_msg[m + 2] * __bfloat162float(w[(HD + m + 2) * MD + t]);
          c3 += s_msg[m + 3] * __bfloat162float(w[(HD + m + 3) * MD + t]);
        }
      } else {
        const float* w = (const float*)Wm;
        for (int h = 0; h < HD; h += 4) {
          c0 += s_ns[h]     * w[(h)     * MD + t];
          c1 += s_ns[h + 1] * w[(h + 1) * MD + t];
          c2 += s_ns[h + 2] * w[(h + 2) * MD + t];
          c3 += s_ns[h + 3] * w[(h + 3) * MD + t];
        }
        for (int m = 0; m < MD; m += 4) {
          c0 += s_msg[m]     * w[(HD + m)     * MD + t];
          c1 += s_msg[m + 1] * w[(HD + m + 1) * MD + t];
          c2 += s_msg[m + 2] * w[(HD + m + 2) * MD + t];
          c3 += s_msg[m + 3] * w[(HD + m + 3) * MD + t];
        }
      }
      scstore(&g_msgb[(size_t)e * MD + t], rbm + ((c0 + c1) + (c2 + c3)));
      asm volatile("s_waitcnt vmcnt(0)" ::: "memory");   // own store at coherence pt
    }
    __syncthreads();                         // stores drained + LDS reuse guard
    if (hc && t == 0)
      __hip_atomic_store(&g_done[e], 1, __ATOMIC_RELAXED,
                         __HIP_MEMORY_SCOPE_AGENT);
  }

  // ---- fused final projection + log_softmax (threads 0..127: pp = t>>6, o = t&63) --
  const int slotF = cnt % HIST;
  if (t < PD * OD) {
    const int pp = t >> 6, o = t & 63;
    float acc = finz(ldin(bd, pp * OD + o, bf));
    for (int h = 0; h < HD; ++h)
      acc += finz(s_hist[slotF][h]) * ldin(Wd, (pp * HD + h) * OD + o, bf);
    acc = finz(acc);
    float mx = acc;
#pragma unroll
    for (int off = 32; off > 0; off >>= 1) mx = fmaxf(mx, __shfl_xor(mx, off, 64));
    float ex = __expf(acc - mx);
    float s = ex;
#pragma unroll
    for (int off = 32; off > 0; off >>= 1) s += __shfl_xor(s, off, 64);
    float r = finz(acc - mx - logf(s));
    const int oi = (pp * NN + n) * OD + o;
    if (bf) ((bf16*)out)[oi] = __float2bfloat16(r);
    else    ((float*)out)[oi] = r;
  }
}

extern "C" void kernel_launch(void* const* d_in, const int* in_sizes, int n_in,
                              void* d_out, int out_size, void* d_ws, size_t ws_size,
                              hipStream_t stream) {
  const void* xa   = d_in[0];
  const int*  nbrs = (const int*)d_in[1];
  const void* fmsg = d_in[2];
  const void* We   = d_in[3];
  const void* be   = d_in[4];
  const void* Wq   = d_in[5];
  const void* bq   = d_in[6];
  const void* Wk   = d_in[7];
  const void* bk   = d_in[8];
  const void* Wr   = d_in[9];
  const void* br   = d_in[10];
  const void* Wm   = d_in[11];
  const void* bm   = d_in[12];
  const void* Wd   = d_in[13];
  const void* bd   = d_in[14];
  const int*  dS   = (const int*)d_in[15];
  (void)d_ws; (void)ws_size; (void)in_sizes; (void)n_in; (void)out_size;

  k_prep<<<dim3(HD + 1 + NN + 1), dim3(1024), 0, stream>>>(
      xa, (const unsigned*)xa, nbrs, dS, We, be, Wq, Wk, Wr, bq, bk);
  k_flow<<<dim3(NN), dim3(256), 0, stream>>>(fmsg, br, Wm, bm, Wd, bd, d_out, dS);
}

// Round 10
// 432.988 us; speedup vs baseline: 1.3011x; 1.3011x over previous
//
#include <hip/hip_runtime.h>
#include <hip/hip_bf16.h>

#define NN 512
#define DEG 8
#define FD 128
#define HD 256
#define MD 256
#define OD 64
#define PD 2
#define HIST 10
#define TOTAL (10 * NN)       /* 5120 queue entries processed */
#define NPAR 648              /* entries with children: i < (TOTAL-S)/8 <= 632 */
#define INV_SQRT_H 0.0625f

typedef __hip_bfloat16 bf16;

// bit-level finite guard (fast-math-proof)
__device__ __forceinline__ float finz(float x) {
  unsigned u = __float_as_uint(x);
  return (((u >> 23) & 0xFFu) == 0xFFu) ? 0.f : x;
}

// runtime-dtype load: bf=1 -> bf16 array, bf=0 -> float array
__device__ __forceinline__ float ldin(const void* p, int idx, int bf) {
  if (bf) return __bfloat162float(((const bf16*)p)[idx]);
  return ((const float*)p)[idx];
}

// device-coherent dword load/store (relaxed agent atomics -> flagged global op,
// bypasses non-coherent L2 for THIS access only; no cache-wide fences anywhere)
__device__ __forceinline__ float scload(const float* p) {
  return __uint_as_float(__hip_atomic_load((const unsigned*)p, __ATOMIC_RELAXED,
                                           __HIP_MEMORY_SCOPE_AGENT));
}
__device__ __forceinline__ void scstore(float* p, float v) {
  __hip_atomic_store((unsigned*)p, __float_as_uint(v), __ATOMIC_RELAXED,
                     __HIP_MEMORY_SCOPE_AGENT);
}

// ---- static device scratch ----
__device__ float g_hist[NN * HIST * HD];    // slot-0 encoded states (k_prep -> k_flow)
__device__ float g_msgb[NPAR * MD];         // messages of entries with children
__device__ float g_WQK[HD * HD];            // Wq @ Wk^T   (kq = msg.WQK + ck)
__device__ float g_WrS[HD * HD];            // sum of 4 Wr row-blocks
__device__ float g_vq[HD];                  // Wq @ bk
__device__ float g_ck[HD];                  // Wk @ bq
__device__ float g_bqk;                     // bq . bk
__device__ int   g_node[TOTAL];
__device__ int   g_done[TOTAL];             // message-ready flags (parents only)
__device__ int   g_dtype;                   // 1 = float tensors are bf16
__device__ int   g_i64;                     // 1 = neighbors int64

__device__ __forceinline__ int decode_S(const int* dS) {
  int r = dS[0];
  if (r >= 1 && r <= NN) return r;
  float f = __int_as_float(r);
  if (f >= 1.f && f <= (float)NN) return (int)f;
  unsigned u = ((unsigned)r & 0xFFFFu) << 16;
  float g = __uint_as_float(u);
  if (g >= 1.f && g <= (float)NN) return (int)g;
  return 64;
}

__device__ __forceinline__ int get_nbr(const int* nbrs, int i64, int n, int d) {
  int v = i64 ? nbrs[2 * (n * DEG + d)] : nbrs[n * DEG + d];
  return (v < 0) ? 0 : (v >= NN ? NN - 1 : v);
}

// wave-parallel dtype probe: same predicate as the validated serial version,
// one ballot over the first 64 words instead of 64 serial loads.
__device__ __forceinline__ int detect_bf(const unsigned* xa_w) {
  const int lane = threadIdx.x & 63;
  unsigned lo = xa_w[lane] & 0xFFFFu;
  float av = fabsf(__uint_as_float(lo << 16));
  unsigned long long m = __ballot(av > 0.000244140625f && av < 64.f);
  return ((int)__popcll(m) >= 32) ? 1 : 0;
}

// ---------------- k_prep: weights fold + encode + BFS, ONE dispatch -----------------
// blocks 0..HD-1: WQK/WrS/vq rows; HD: ck/bqk; HD+1..HD+NN: encode; HD+NN+1: BFS.
// NEW (round 10): the WQK blocks' Wk reads were fully UNCOALESCED (thread col reads
// Wk[col*HD+h]: 64 lanes -> 64 cache lines per instruction, 256 iters). Now Wk^T is
// staged through LDS in 32-wide h-tiles: global reads coalesced (hh fast axis),
// transpose write conflict-free (257-word pitch), compute reads stride-1.
__global__ void __launch_bounds__(1024)
k_prep(const void* __restrict__ xa, const unsigned* __restrict__ xa_w,
       const int* __restrict__ nbrs, const int* __restrict__ dS,
       const void* __restrict__ We, const void* __restrict__ be,
       const void* __restrict__ Wq, const void* __restrict__ Wk,
       const void* __restrict__ Wr, const void* __restrict__ bq,
       const void* __restrict__ bk) {
  const int b = blockIdx.x, t = threadIdx.x;
  const int col = t & 255, grp = t >> 8;
  const int wave = t >> 6, lane = t & 63;
  const int bf = detect_bf(xa_w);
  if (t < 8) { int fi = 8 * b + t; if (fi < TOTAL) g_done[fi] = 0; }
  __shared__ float sw[HD];
  __shared__ float sp[4][HD];
  __shared__ float sr[16];
  __shared__ float s_wkT[32][HD + 1];        // Wk^T tile, 32.9 KB, conflict-free
  __shared__ int s_node[TOTAL];              // BFS block only (20 KB)
  if (b < HD) {
    if (grp == 0) sw[col] = ldin(Wq, b * HD + col, bf);
    __syncthreads();
    if (grp == 1) {                              // vq[b] partial (overlapped)
      float pv = sw[col] * ldin(bk, col, bf);
#pragma unroll
      for (int off = 32; off > 0; off >>= 1) pv += __shfl_down(pv, off, 64);
      if (lane == 0) sr[wave] = pv;              // waves 4..7
    }
    if (grp == 2) {                              // WrS row b (overlapped, coalesced)
      float s = 0.f;
#pragma unroll
      for (int q = 0; q < 4; ++q) s += ldin(Wr, (size_t)(q * HD + b) * HD + col, bf);
      g_WrS[b * HD + col] = s;
    }
    // WQK[b][col] = Wq row b . Wk row col, via LDS-staged Wk^T tiles
    float acc0 = 0.f, acc1 = 0.f;
    const int hh = t & 31, r0 = t >> 5;          // staging coords (r0: 0..31)
    for (int h0 = 0; h0 < HD; h0 += 32) {
#pragma unroll
      for (int rr = 0; rr < 8; ++rr) {           // coalesced: hh is the fast axis
        const int row = rr * 32 + r0;
        s_wkT[hh][row] = ldin(Wk, row * HD + h0 + hh, bf);
      }
      __syncthreads();
      const int hb = grp * 8;                    // grp's 8-slice of this tile
#pragma unroll
      for (int i = 0; i < 8; i += 2) {
        acc0 += sw[h0 + hb + i]     * s_wkT[hb + i][col];
        acc1 += sw[h0 + hb + i + 1] * s_wkT[hb + i + 1][col];
      }
      __syncthreads();                           // tile reuse guard
    }
    sp[grp][col] = acc0 + acc1;
    __syncthreads();
    if (grp == 0)
      g_WQK[b * HD + col] = (sp[0][col] + sp[1][col]) + (sp[2][col] + sp[3][col]);
    if (t == 0) g_vq[b] = (sr[4] + sr[5]) + (sr[6] + sr[7]);
  } else if (b == HD) {
    {                                            // ck[col] = Wk row col . bq, split 4
      const int h0 = grp * 64;
      float a0 = 0.f, a1 = 0.f, a2 = 0.f, a3 = 0.f;
      for (int h = 0; h < 64; h += 4) {
        a0 += ldin(Wk, col * HD + h0 + h,     bf) * ldin(bq, h0 + h,     bf);
        a1 += ldin(Wk, col * HD + h0 + h + 1, bf) * ldin(bq, h0 + h + 1, bf);
        a2 += ldin(Wk, col * HD + h0 + h + 2, bf) * ldin(bq, h0 + h + 2, bf);
        a3 += ldin(Wk, col * HD + h0 + h + 3, bf) * ldin(bq, h0 + h + 3, bf);
      }
      sp[grp][col] = (a0 + a1) + (a2 + a3);
    }
    if (grp == 1) {
      float pb = ldin(bq, col, bf) * ldin(bk, col, bf);
#pragma unroll
      for (int off = 32; off > 0; off >>= 1) pb += __shfl_down(pb, off, 64);
      if (lane == 0) sr[wave] = pb;              // waves 4..7
    }
    __syncthreads();
    if (grp == 0)
      g_ck[col] = (sp[0][col] + sp[1][col]) + (sp[2][col] + sp[3][col]);
    if (t == 0) g_bqk = (sr[4] + sr[5]) + (sr[6] + sr[7]);
  } else if (b <= HD + NN) {                     // encode node n, K=FD split 4
    const int n = b - HD - 1;
    if (t < FD) sw[t] = ldin(xa, n * FD + t, bf);
    __syncthreads();
    const int f0 = grp * 32;
    float a0 = 0.f, a1 = 0.f, a2 = 0.f, a3 = 0.f;
    for (int f = 0; f < 32; f += 4) {
      a0 += sw[f0 + f]     * ldin(We, (f0 + f)     * HD + col, bf);
      a1 += sw[f0 + f + 1] * ldin(We, (f0 + f + 1) * HD + col, bf);
      a2 += sw[f0 + f + 2] * ldin(We, (f0 + f + 2) * HD + col, bf);
      a3 += sw[f0 + f + 3] * ldin(We, (f0 + f + 3) * HD + col, bf);
    }
    sp[grp][col] = (a0 + a1) + (a2 + a3);
    __syncthreads();
    if (grp == 0)
      g_hist[(size_t)(n * HIST) * HD + col] =
          ldin(be, col, bf) + (sp[0][col] + sp[1][col]) + (sp[2][col] + sp[3][col]);
  } else {                                       // BFS queue expansion
    if (t == 0) g_dtype = bf;
    bool c8 = (lane < 8) ? (nbrs[2 * lane + 1] == 0) : true;
    unsigned long long im = __ballot(c8);
    const int i64 = ((im & 0xFFull) == 0xFFull) ? 1 : 0;
    if (t == 0) g_i64 = i64;
    const int S = decode_S(dS);
    for (int i = t; i < S; i += 1024) s_node[i] = i;
    __syncthreads();
    int done = S;
    while (done < TOTAL) {                       // message tree, depth ~4
      long long nd = (long long)S + 8LL * (long long)done;
      int new_done = nd > (long long)TOTAL ? TOTAL : (int)nd;
      for (int i = done + t; i < new_done; i += 1024)
        s_node[i] = get_nbr(nbrs, i64, s_node[(i - S) >> 3], (i - S) & 7);
      __syncthreads();
      done = new_done;
    }
    for (int i = t; i < TOTAL; i += 1024) g_node[i] = s_node[i];
  }
}

// ---------------- dataflow executor: ONE BLOCK PER NODE + fused output --------------
// EXACT round-8 body (measured best: 316 us, 52 VGPR, FETCH 7 MB): proven scalar
// matvecs + message prefetch + invariant hoisting + fused projection. Round-9's
// pair-interleaved float2 matvec REGRESSED (431 us, longer VALU dep chain per load,
// fewer independent loads in flight) and is reverted.
// Residency: 512 blocks, launch_bounds(256,2), ~35 KB LDS -> 2 blocks/CU = all 512
// resident. Deps of entry e have smaller queue index -> progress by induction.
__global__ void __launch_bounds__(256, 2)
k_flow(const void* __restrict__ fmsg, const void* __restrict__ br_,
       const void* __restrict__ Wm, const void* __restrict__ bm,
       const void* __restrict__ Wd, const void* __restrict__ bd,
       void* __restrict__ out, const int* __restrict__ dS) {
  const int n = blockIdx.x;
  const int t = threadIdx.x;
  const int wave = t >> 6, lane = t & 63;
  const int S = decode_S(dS);
  const int bf = g_dtype;
  __shared__ float s_hist[HIST][HD];         // node-n ring buffer, column t private
  __shared__ float s_msgb2[2][MD];           // double-buffered message
  __shared__ float s_vals[HD];
  __shared__ float s_ns[HD];
  __shared__ float s_red[4][HIST + 1];
  __shared__ int   s_list[TOTAL];            // safe upper bound (20 KB)
  __shared__ int   s_cnt;
  __shared__ int   s_pf[2];                  // prefetch-done flag per buffer parity

  // loop invariants in registers
  const float rck = g_ck[t];
  const float rvq = g_vq[t];
  const float rbqk = g_bqk;
  const float rbr = ldin(br_, t, bf);
  const float rbm = ldin(bm, t, bf);

#pragma unroll
  for (int j = 1; j < HIST; ++j) s_hist[j][t] = 0.f;   // invalid slots read as 0
  s_hist[0][t] = finz(g_hist[(size_t)n * HIST * HD + t]);  // encoded state

  if (wave == 0) {                           // build node-n entry list (queue order)
    int k = 0;
    for (int base = 0; base < TOTAL; base += 64) {
      int nd = g_node[base + lane];
      unsigned long long m = __ballot(nd == n);
      if (nd == n) {
        unsigned long long below = m & ((1ull << lane) - 1ull);
        s_list[k + (int)__popcll(below)] = base + lane;
      }
      k += (int)__popcll(m);
    }
    if (lane == 0) { s_cnt = k; s_pf[0] = 0; s_pf[1] = 0; }
  }
  __syncthreads();
  const int cnt = s_cnt;

  for (int k = 0; k < cnt; ++k) {
    const int e = s_list[k];
    const int c = k + 1;
    const int v = (c < HIST) ? c : HIST;
    const int slot = c % HIST;
    const bool hc = (S + 8 * e) < TOTAL;
    float* s_msg = s_msgb2[k & 1];
    const int havepf = s_pf[k & 1];          // written by t0 last step; end barrier

    // t0: decide prefetch for k+1 (flag may flip later -> blocking path catches it)
    if (t == 0) {
      int pf = 0;
      if (k + 1 < cnt) {
        const int e2 = s_list[k + 1];
        if (e2 < S) pf = 1;
        else pf = (__hip_atomic_load(&g_done[(e2 - S) >> 3], __ATOMIC_RELAXED,
                                     __HIP_MEMORY_SCOPE_AGENT) != 0);
      }
      s_pf[(k + 1) & 1] = pf;
    }

    // ---- acquire message (skipped when prefetched last step) ----
    if (!havepf) {
      if (e < S) {
        s_msg[t] = finz(ldin(fmsg, e * MD + t, bf));
      } else {
        const int p = (e - S) >> 3;
        if (t == 0)
          while (__hip_atomic_load(&g_done[p], __ATOMIC_RELAXED,
                                   __HIP_MEMORY_SCOPE_AGENT) == 0)
            __builtin_amdgcn_s_sleep(4);
        __syncthreads();                     // flag seen by whole block
        s_msg[t] = finz(scload(g_msgb + (size_t)p * MD + t));
      }
      __syncthreads();
    }

    // ---- kq[t] = msg . WQK[:,t] + ck[t] (4-acc, proven scalar walk) ----
    float a0 = 0.f, a1 = 0.f, a2 = 0.f, a3 = 0.f;
    for (int m = 0; m < MD; m += 4) {
      a0 += s_msg[m]     * g_WQK[(m)     * HD + t];
      a1 += s_msg[m + 1] * g_WQK[(m + 1) * HD + t];
      a2 += s_msg[m + 2] * g_WQK[(m + 2) * HD + t];
      a3 += s_msg[m + 3] * g_WQK[(m + 3) * HD + t];
    }
    const float kq = rck + ((a0 + a1) + (a2 + a3));

    // ---- 11 dot-products via wave shuffle + LDS fold ----
    float part[HIST + 1];
#pragma unroll
    for (int j = 0; j < HIST; ++j) part[j] = s_hist[j][t] * kq;
    part[HIST] = s_msg[t] * rvq;
#pragma unroll
    for (int o = 32; o > 0; o >>= 1) {
#pragma unroll
      for (int j = 0; j <= HIST; ++j) part[j] += __shfl_down(part[j], o, 64);
    }
    if (lane == 0) {
#pragma unroll
      for (int j = 0; j <= HIST; ++j) s_red[wave][j] = part[j];
    }
    __syncthreads();                         // scores-fold barrier (s_pf visible too)

    // ---- issue next-message prefetch into a register (write to LDS deferred) ----
    const int dopf = s_pf[(k + 1) & 1];
    float pm = 0.f;
    if (dopf) {
      const int e2 = s_list[k + 1];
      pm = (e2 < S) ? ldin(fmsg, e2 * MD + t, bf)
                    : scload(g_msgb + (size_t)((e2 - S) >> 3) * MD + t);
    }

    float sc[HIST + 1];
#pragma unroll
    for (int j = 0; j <= HIST; ++j)
      sc[j] = (s_red[0][j] + s_red[1][j]) + (s_red[2][j] + s_red[3][j]);
    const float bkq = sc[HIST] + rbqk;
    float lg[HIST];
#pragma unroll
    for (int j = 0; j < HIST; ++j)
      lg[j] = (j < v) ? ((sc[j] + bkq) * INV_SQRT_H) : -1e30f;
    float mx = lg[0];
#pragma unroll
    for (int j = 1; j < HIST; ++j) mx = fmaxf(mx, lg[j]);
    float e_[HIST], den = 0.f;
#pragma unroll
    for (int j = 0; j < HIST; ++j) { e_[j] = __expf(lg[j] - mx); den += e_[j]; }
    const float iden = 1.0f / den;
    float val = 0.f;
#pragma unroll
    for (int j = 0; j < HIST; ++j) val += e_[j] * s_hist[j][t];
    s_vals[t] = val * iden;
    __syncthreads();

    // ---- ns = vals @ WrS + br ----
    float b0 = 0.f, b1 = 0.f, b2 = 0.f, b3 = 0.f;
    for (int h = 0; h < HD; h += 4) {
      b0 += s_vals[h]     * g_WrS[(h)     * HD + t];
      b1 += s_vals[h + 1] * g_WrS[(h + 1) * HD + t];
      b2 += s_vals[h + 2] * g_WrS[(h + 2) * HD + t];
      b3 += s_vals[h + 3] * g_WrS[(h + 3) * HD + t];
    }
    const float ns = rbr + ((b0 + b1) + (b2 + b3));
    s_hist[slot][t] = ns;                    // column-private
    if (hc) s_ns[t] = ns;
    if (dopf) s_msgb2[(k + 1) & 1][t] = finz(pm);  // deferred prefetch commit
    __syncthreads();                         // s_ns + prefetched msg visible

    // ---- newmessage = [ns; msg] @ Wm + bm (parents only) ----
    if (hc) {
      float c0 = 0.f, c1 = 0.f, c2 = 0.f, c3 = 0.f;
      if (bf) {
        const bf16* w = (const bf16*)Wm;
        for (int h = 0; h < HD; h += 4) {
          c0 += s_ns[h]     * __bfloat162float(w[(h)     * MD + t]);
          c1 += s_ns[h + 1] * __bfloat162float(w[(h + 1) * MD + t]);
          c2 += s_ns[h + 2] * __bfloat162float(w[(h + 2) * MD + t]);
          c3 += s_ns[h + 3] * __bfloat162float(w[(h + 3) * MD + t]);
        }
        for (int m = 0; m < MD; m += 4) {
          c0 += s_msg[m]     * __bfloat162float(w[(HD + m)     * MD + t]);
          c1 += s_msg[m + 1] * __bfloat162float(w[(HD + m + 1) * MD + t]);
          c2 += s_msg[m + 2] * __bfloat162float(w[(HD + m + 2) * MD + t]);
          c3 += s_msg[m + 3] * __bfloat162float(w[(HD + m + 3) * MD + t]);
        }
      } else {
        const float* w = (const float*)Wm;
        for (int h = 0; h < HD; h += 4) {
          c0 += s_ns[h]     * w[(h)     * MD + t];
          c1 += s_ns[h + 1] * w[(h + 1) * MD + t];
          c2 += s_ns[h + 2] * w[(h + 2) * MD + t];
          c3 += s_ns[h + 3] * w[(h + 3) * MD + t];
        }
        for (int m = 0; m < MD; m += 4) {
          c0 += s_msg[m]     * w[(HD + m)     * MD + t];
          c1 += s_msg[m + 1] * w[(HD + m + 1) * MD + t];
          c2 += s_msg[m + 2] * w[(HD + m + 2) * MD + t];
          c3 += s_msg[m + 3] * w[(HD + m + 3) * MD + t];
        }
      }
      scstore(&g_msgb[(size_t)e * MD + t], rbm + ((c0 + c1) + (c2 + c3)));
      asm volatile("s_waitcnt vmcnt(0)" ::: "memory");   // own store at coherence pt
    }
    __syncthreads();                         // stores drained + LDS reuse guard
    if (hc && t == 0)
      __hip_atomic_store(&g_done[e], 1, __ATOMIC_RELAXED,
                         __HIP_MEMORY_SCOPE_AGENT);
  }

  // ---- fused final projection + log_softmax (threads 0..127: pp = t>>6, o = t&63) --
  const int slotF = cnt % HIST;
  if (t < PD * OD) {
    const int pp = t >> 6, o = t & 63;
    float acc = finz(ldin(bd, pp * OD + o, bf));
    for (int h = 0; h < HD; ++h)
      acc += finz(s_hist[slotF][h]) * ldin(Wd, (pp * HD + h) * OD + o, bf);
    acc = finz(acc);
    float mx = acc;
#pragma unroll
    for (int off = 32; off > 0; off >>= 1) mx = fmaxf(mx, __shfl_xor(mx, off, 64));
    float ex = __expf(acc - mx);
    float s = ex;
#pragma unroll
    for (int off = 32; off > 0; off >>= 1) s += __shfl_xor(s, off, 64);
    float r = finz(acc - mx - logf(s));
    const int oi = (pp * NN + n) * OD + o;
    if (bf) ((bf16*)out)[oi] = __float2bfloat16(r);
    else    ((float*)out)[oi] = r;
  }
}

extern "C" void kernel_launch(void* const* d_in, const int* in_sizes, int n_in,
                              void* d_out, int out_size, void* d_ws, size_t ws_size,
                              hipStream_t stream) {
  const void* xa   = d_in[0];
  const int*  nbrs = (const int*)d_in[1];
  const void* fmsg = d_in[2];
  const void* We   = d_in[3];
  const void* be   = d_in[4];
  const void* Wq   = d_in[5];
  const void* bq   = d_in[6];
  const void* Wk   = d_in[7];
  const void* bk   = d_in[8];
  const void* Wr   = d_in[9];
  const void* br   = d_in[10];
  const void* Wm   = d_in[11];
  const void* bm   = d_in[12];
  const void* Wd   = d_in[13];
  const void* bd   = d_in[14];
  const int*  dS   = (const int*)d_in[15];
  (void)d_ws; (void)ws_size; (void)in_sizes; (void)n_in; (void)out_size;

  k_prep<<<dim3(HD + 1 + NN + 1), dim3(1024), 0, stream>>>(
      xa, (const unsigned*)xa, nbrs, dS, We, be, Wq, Wk, Wr, bq, bk);
  k_flow<<<dim3(NN), dim3(256), 0, stream>>>(fmsg, br, Wm, bm, Wd, bd, d_out, dS);
}